// Round 3
// baseline (272.515 us; speedup 1.0000x reference)
//
#include <hip/hip_runtime.h>
#include <hip/hip_bf16.h>

#define FEATURES 1024
#define SEGS 256                    // float4 segments per row (1024 floats / 4)
#define NROWS (8 * 2048)            // 16384
#define NCHUNK (NROWS * SEGS)       // 4,194,304 float4 chunks
#define TPB 256
#define BLOCKS 2048
#define NTHREADS (BLOCKS * TPB)     // 524,288 -> exactly 8 chunks per thread
#define ITERS 8

// Chunk-stride gather: each thread copies 8 independent float4 chunks.
// out[g] = w[idxes[g >> 8] * 256 + (g & 255)] for g in [0, NCHUNK).
// A wave's 64 consecutive chunks are a contiguous 1 KiB read within one
// weight row (rows are 256-chunk aligned), so gathers stay coalesced.
__global__ __launch_bounds__(TPB) void embed_gather(
    const int* __restrict__ idxes,
    const float4* __restrict__ w,     // weight as [PAGES][256] float4
    float4* __restrict__ out)         // out as [NROWS][256] float4
{
    const int g0 = blockIdx.x * TPB + threadIdx.x;

    int idx[ITERS];
    int seg[ITERS];
#pragma unroll
    for (int i = 0; i < ITERS; ++i) {
        const int g = g0 + i * NTHREADS;
        const int row = g >> 8;       // chunk -> output row
        seg[i] = g & 255;             // chunk -> segment within row
        idx[i] = idxes[row];          // independent index loads
    }

    float4 v[ITERS];
#pragma unroll
    for (int i = 0; i < ITERS; ++i)   // 8 independent gathers in flight
        v[i] = w[(size_t)idx[i] * SEGS + seg[i]];

#pragma unroll
    for (int i = 0; i < ITERS; ++i)   // coalesced stores
        out[(size_t)(g0 + i * NTHREADS)] = v[i];
}

extern "C" void kernel_launch(void* const* d_in, const int* in_sizes, int n_in,
                              void* d_out, int out_size, void* d_ws, size_t ws_size,
                              hipStream_t stream) {
    const int* idxes = (const int*)d_in[0];         // [8,2048] int32
    const float4* weight = (const float4*)d_in[1];  // [50257,1024] fp32 rows
    float4* out = (float4*)d_out;                   // [8,2048,1024] fp32

    embed_gather<<<BLOCKS, TPB, 0, stream>>>(idxes, weight, out);
}